// Round 8
// baseline (345.906 us; speedup 1.0000x reference)
//
#include <hip/hip_runtime.h>
#include <hip/hip_fp16.h>

#define BB   8
#define CC   1024
#define NN   4096
#define KL   32
#define KK   1024
#define XMINF (-15.0f)
#define EPSF  1e-6f
#define WS_SCALE  33554432.0f      // 2^25 fixed point for weight sums
#define WS_INV    (1.0f/33554432.0f)

// Single fused kernel: one block per (batch, 4-channel group). No workspace,
// no inter-kernel or inter-block communication — output is a pure function of
// d_in on every call.
//
// LDS layout (single object -> known byte offsets for raw DS atomics):
//   [    0,  4096)  half2 acc01[KK]  (ch c0 in lo16, c1 in hi16), f16 accum
//   [ 4096,  8192)  half2 acc23[KK]  (ch c2, c3)
//   [ 8192, 12288)  u32   wsl[KK]    2^25 fixed-point weight sums (exact)
// Feature accumulation uses raw ds_pk_add_f16 (native packed-f16 LDS atomic,
// 2 channels per op) — HIP's f32 atomicAdd lowers to a CAS loop (round-1
// evidence: ~198 cyc/wave-op), so we emit the instruction directly.
// 12 atomics/pixel serve 4 channels (3/ch vs round 7's 6/ch).
__global__ __launch_bounds__(256, 6) void WLP_fused_kernel(
    const float*  __restrict__ feats,      // (B, CC, NN)
    const float2* __restrict__ coord,      // (B, N)
    float*        __restrict__ world,      // (B, CC, KK)
    float*        __restrict__ weights_out)// (B, 16, KK)
{
  const int bg  = blockIdx.x;          // b * 256 + g4
  const int b   = bg >> 8;
  const int g4  = bg & 255;
  const int c0  = g4 << 2;
  const int tid = threadIdx.x;

  __shared__ uint4 lds_raw4[12288 / 16];
  unsigned*  wsl   = (unsigned*)((char*)lds_raw4 + 8192);
  const unsigned lds_base = (unsigned)(size_t)(char*)lds_raw4;  // LDS byte addr

  lds_raw4[tid]       = make_uint4(0, 0, 0, 0);
  lds_raw4[256 + tid] = make_uint4(0, 0, 0, 0);
  lds_raw4[512 + tid] = make_uint4(0, 0, 0, 0);
  __syncthreads();

  const float4* f0 = (const float4*)(feats + (((size_t)(b << 10) | c0) << 12));
  const float4* f1 = f0 + 1024;        // one channel = 4096 floats = 1024 float4
  const float4* f2 = f0 + 2048;
  const float4* f3 = f0 + 3072;
  const float4* cm = (const float4*)(coord + ((size_t)b << 12));

  for (int it = 0; it < 4; ++it) {
    int q = it * 256 + tid;            // pixel-quad index
    float4 cA = cm[2 * q];             // coords for pixels 4q, 4q+1
    float4 cB = cm[2 * q + 1];         // coords for pixels 4q+2, 4q+3
    float4 a  = f0[q], bb = f1[q], cc2 = f2[q], dd = f3[q];

    #define PKADD(off_lit, va, vb) { \
      unsigned hu_; \
      asm("v_cvt_pkrtz_f16_f32 %0, %1, %2" : "=v"(hu_) : "v"(va), "v"(vb)); \
      asm volatile("ds_pk_add_f16 %0, %1 offset:" off_lit \
                   :: "v"(o01_), "v"(hu_) : "memory"); }

    #define SPLAT(px, py, v0, v1, v2, v3) { \
      float gx = ((px) - XMINF) * (31.0f / 30.0f); \
      float gy = ((py) - XMINF) * (31.0f / 30.0f); \
      int cx = min(max((int)floorf(gx), 0), 30); \
      int cy = min(max((int)floorf(gy), 0), 30); \
      float wx = gx - (float)cx, wy = gy - (float)cy; \
      float ex = 1.0f - wx,      ey = 1.0f - wy; \
      float w00 = ex*ey, w10 = wx*ey, w01 = ex*wy, w11 = wx*wy; \
      int bu = (cy << 5) + cx; \
      atomicAdd(&wsl[bu],      (unsigned)__float2int_rn(w00 * WS_SCALE)); \
      atomicAdd(&wsl[bu+1],    (unsigned)__float2int_rn(w10 * WS_SCALE)); \
      atomicAdd(&wsl[bu+KL],   (unsigned)__float2int_rn(w01 * WS_SCALE)); \
      atomicAdd(&wsl[bu+KL+1], (unsigned)__float2int_rn(w11 * WS_SCALE)); \
      unsigned o01_ = lds_base + ((unsigned)bu << 2); \
      PKADD("0",    (v0)*w00, (v1)*w00)  PKADD("4096", (v2)*w00, (v3)*w00) \
      PKADD("4",    (v0)*w10, (v1)*w10)  PKADD("4100", (v2)*w10, (v3)*w10) \
      PKADD("128",  (v0)*w01, (v1)*w01)  PKADD("4224", (v2)*w01, (v3)*w01) \
      PKADD("132",  (v0)*w11, (v1)*w11)  PKADD("4228", (v2)*w11, (v3)*w11) }

    SPLAT(cA.x, cA.y, a.x, bb.x, cc2.x, dd.x)
    SPLAT(cA.z, cA.w, a.y, bb.y, cc2.y, dd.y)
    SPLAT(cB.x, cB.y, a.z, bb.z, cc2.z, dd.z)
    SPLAT(cB.z, cB.w, a.w, bb.w, cc2.w, dd.w)
    #undef SPLAT
    #undef PKADD
  }
  __syncthreads();   // drains lgkmcnt -> all ds_pk_add results visible

  // epilogue: thread owns cells 4t..4t+3; one divide per cell, 4 channels
  const __half2* A01 = (const __half2*)lds_raw4;
  const __half2* A23 = (const __half2*)((char*)lds_raw4 + 4096);
  float ch0[4], ch1[4], ch2[4], ch3[4], wv[4];
  #pragma unroll
  for (int j = 0; j < 4; ++j) {
    int cell = (tid << 2) | j;
    __half2 p = A01[cell], r = A23[cell];
    float w = (float)wsl[cell] * WS_INV;
    float inv = 1.0f / fmaxf(w, EPSF);
    wv[j]  = w;
    ch0[j] = __low2float(p)  * inv;
    ch1[j] = __high2float(p) * inv;
    ch2[j] = __low2float(r)  * inv;
    ch3[j] = __high2float(r) * inv;
  }
  const size_t ob = ((size_t)(b << 10) | c0) << 10;
  ((float4*)(world + ob))[tid]          = make_float4(ch0[0], ch0[1], ch0[2], ch0[3]);
  ((float4*)(world + ob + KK))[tid]     = make_float4(ch1[0], ch1[1], ch1[2], ch1[3]);
  ((float4*)(world + ob + 2 * KK))[tid] = make_float4(ch2[0], ch2[1], ch2[2], ch2[3]);
  ((float4*)(world + ob + 3 * KK))[tid] = make_float4(ch3[0], ch3[1], ch3[2], ch3[3]);

  // first 16 groups of each batch also emit the broadcast weights output
  if (g4 < 16)
    ((float4*)(weights_out + ((size_t)(b * 16 + g4) << 10)))[tid] =
        make_float4(wv[0], wv[1], wv[2], wv[3]);
}

extern "C" void kernel_launch(void* const* d_in, const int* in_sizes, int n_in,
                              void* d_out, int out_size, void* d_ws, size_t ws_size,
                              hipStream_t stream) {
  const float*  feats = (const float*)d_in[0];   // (B,T,D,HP,WP) = (B,1024,4096)
  const float2* coord = (const float2*)d_in[1];  // (B,HP,WP) float2
  float* out = (float*)d_out;
  float* world       = out;                          // B*CC*KK
  float* weights_out = out + (size_t)BB * CC * KK;   // B*16*KK

  (void)d_ws; (void)ws_size;  // unused: no workspace, no inter-kernel state

  WLP_fused_kernel<<<BB * CC / 4, 256, 0, stream>>>(feats, coord, world, weights_out);
}

// Round 9
// 39.514 us; speedup vs baseline: 8.7541x; 8.7541x over previous
//
#include <hip/hip_runtime.h>

#define BB   8
#define CC   1024
#define NN   4096
#define KL   32
#define KK   1024
#define XMINF (-15.0f)
#define EPSF  1e-6f
#define ACC_SCALE 4194304.0f       // 2^22 fixed point for feature accum
#define ACC_INV   (1.0f/4194304.0f)
#define WS_SCALE  33554432.0f      // 2^25 fixed point for weight sums
#define WS_INV    (1.0f/33554432.0f)

// Pack two signed fixed-point contributions into one u64 addend.
// Sum of encodings == encoding of sums (int64 arithmetic, exact mod 2^64);
// decode splits 32/32 with the borrow fix: hi += (lo_signed < 0).
__device__ __forceinline__ unsigned long long packq(float a, float b) {
  long long lo = (long long)__float2int_rn(a * ACC_SCALE);
  long long hi = (long long)__float2int_rn(b * ACC_SCALE);
  return (unsigned long long)((hi << 32) + lo);
}

// Single fused kernel: one block per (batch, 4-channel group). No workspace,
// no inter-block communication — output is a pure function of d_in on every
// call (integer atomics => order-independent => replay-deterministic).
//
// Per pixel: 4 u32 wsum atomics + 8 u64 acc atomics serve 4 channels
// (3 atomic instrs/channel vs round 7's 6). LDS = 20 KB -> 8 blocks/CU,
// 32 waves/CU. All accumulation in exact integer fixed point.
__global__ __launch_bounds__(256, 8) void WLP_fused_kernel(
    const float*  __restrict__ feats,      // (B, CC, NN)
    const float2* __restrict__ coord,      // (B, N)
    float*        __restrict__ world,      // (B, CC, KK)
    float*        __restrict__ weights_out)// (B, 16, KK)
{
  const int bg  = blockIdx.x;          // b * 256 + g4
  const int b   = bg >> 8;
  const int g4  = bg & 255;
  const int c0  = g4 << 2;
  const int tid = threadIdx.x;

  __shared__ unsigned long long acc01[KK];  // 8 KB: ch c0 in lo32, c1 in hi32
  __shared__ unsigned long long acc23[KK];  // 8 KB: ch c2, c3
  __shared__ unsigned           wsl[KK];    // 4 KB: 2^25 fixed-point wsum
  ((uint4*)acc01)[tid]       = make_uint4(0, 0, 0, 0);
  ((uint4*)acc01)[256 + tid] = make_uint4(0, 0, 0, 0);
  ((uint4*)acc23)[tid]       = make_uint4(0, 0, 0, 0);
  ((uint4*)acc23)[256 + tid] = make_uint4(0, 0, 0, 0);
  ((uint4*)wsl)[tid]         = make_uint4(0, 0, 0, 0);
  __syncthreads();

  const float4* f0 = (const float4*)(feats + (((size_t)(b << 10) | c0) << 12));
  const float4* f1 = f0 + 1024;        // one channel = 4096 floats = 1024 float4
  const float4* f2 = f0 + 2048;
  const float4* f3 = f0 + 3072;
  const float4* cm = (const float4*)(coord + ((size_t)b << 12));

  for (int it = 0; it < 4; ++it) {
    int q = it * 256 + tid;            // pixel-quad index
    float4 cA = cm[2 * q];             // coords for pixels 4q, 4q+1
    float4 cB = cm[2 * q + 1];         // coords for pixels 4q+2, 4q+3
    float4 a  = f0[q], bb = f1[q], cc = f2[q], dd = f3[q];

    #define SPLAT(px, py, v0, v1, v2, v3) { \
      float gx = ((px) - XMINF) * (31.0f / 30.0f); \
      float gy = ((py) - XMINF) * (31.0f / 30.0f); \
      int cx = min(max((int)floorf(gx), 0), 30); \
      int cy = min(max((int)floorf(gy), 0), 30); \
      float wx = gx - (float)cx, wy = gy - (float)cy; \
      float ex = 1.0f - wx,      ey = 1.0f - wy; \
      float w00 = ex*ey, w10 = wx*ey, w01 = ex*wy, w11 = wx*wy; \
      int bu = (cy << 5) + cx; \
      atomicAdd(&wsl[bu],      (unsigned)__float2int_rn(w00 * WS_SCALE)); \
      atomicAdd(&wsl[bu+1],    (unsigned)__float2int_rn(w10 * WS_SCALE)); \
      atomicAdd(&wsl[bu+KL],   (unsigned)__float2int_rn(w01 * WS_SCALE)); \
      atomicAdd(&wsl[bu+KL+1], (unsigned)__float2int_rn(w11 * WS_SCALE)); \
      atomicAdd(&acc01[bu],        packq((v0)*w00, (v1)*w00)); \
      atomicAdd(&acc23[bu],        packq((v2)*w00, (v3)*w00)); \
      atomicAdd(&acc01[bu+1],      packq((v0)*w10, (v1)*w10)); \
      atomicAdd(&acc23[bu+1],      packq((v2)*w10, (v3)*w10)); \
      atomicAdd(&acc01[bu+KL],     packq((v0)*w01, (v1)*w01)); \
      atomicAdd(&acc23[bu+KL],     packq((v2)*w01, (v3)*w01)); \
      atomicAdd(&acc01[bu+KL+1],   packq((v0)*w11, (v1)*w11)); \
      atomicAdd(&acc23[bu+KL+1],   packq((v2)*w11, (v3)*w11)); \
    }
    SPLAT(cA.x, cA.y, a.x, bb.x, cc.x, dd.x)
    SPLAT(cA.z, cA.w, a.y, bb.y, cc.y, dd.y)
    SPLAT(cB.x, cB.y, a.z, bb.z, cc.z, dd.z)
    SPLAT(cB.z, cB.w, a.w, bb.w, cc.w, dd.w)
    #undef SPLAT
  }
  __syncthreads();

  // epilogue: thread owns cells 4t..4t+3; decode u64 pairs, one divide/cell
  float ch0[4], ch1[4], ch2[4], ch3[4], wv[4];
  #pragma unroll
  for (int j = 0; j < 4; ++j) {
    int cell = (tid << 2) | j;
    unsigned long long A = acc01[cell], B = acc23[cell];
    int lo0 = (int)(unsigned)(A & 0xffffffffull);
    int hi0 = (int)(unsigned)(A >> 32);  hi0 += (lo0 < 0);
    int lo1 = (int)(unsigned)(B & 0xffffffffull);
    int hi1 = (int)(unsigned)(B >> 32);  hi1 += (lo1 < 0);
    float w = (float)wsl[cell] * WS_INV;
    float inv = ACC_INV / fmaxf(w, EPSF);
    wv[j]  = w;
    ch0[j] = (float)lo0 * inv;
    ch1[j] = (float)hi0 * inv;
    ch2[j] = (float)lo1 * inv;
    ch3[j] = (float)hi1 * inv;
  }
  const size_t ob = ((size_t)(b << 10) | c0) << 10;
  ((float4*)(world + ob))[tid]          = make_float4(ch0[0], ch0[1], ch0[2], ch0[3]);
  ((float4*)(world + ob + KK))[tid]     = make_float4(ch1[0], ch1[1], ch1[2], ch1[3]);
  ((float4*)(world + ob + 2 * KK))[tid] = make_float4(ch2[0], ch2[1], ch2[2], ch2[3]);
  ((float4*)(world + ob + 3 * KK))[tid] = make_float4(ch3[0], ch3[1], ch3[2], ch3[3]);

  // first 16 groups of each batch also emit the broadcast weights output
  if (g4 < 16)
    ((float4*)(weights_out + ((size_t)(b * 16 + g4) << 10)))[tid] =
        make_float4(wv[0], wv[1], wv[2], wv[3]);
}

extern "C" void kernel_launch(void* const* d_in, const int* in_sizes, int n_in,
                              void* d_out, int out_size, void* d_ws, size_t ws_size,
                              hipStream_t stream) {
  const float*  feats = (const float*)d_in[0];   // (B,T,D,HP,WP) = (B,1024,4096)
  const float2* coord = (const float2*)d_in[1];  // (B,HP,WP) float2
  float* out = (float*)d_out;
  float* world       = out;                          // B*CC*KK
  float* weights_out = out + (size_t)BB * CC * KK;   // B*16*KK

  (void)d_ws; (void)ws_size;  // unused: no workspace, no inter-kernel state

  WLP_fused_kernel<<<BB * CC / 4, 256, 0, stream>>>(feats, coord, world, weights_out);
}